// Round 1
// baseline (746.135 us; speedup 1.0000x reference)
//
#include <hip/hip_runtime.h>

#define NROWS 262144
#define E 256
#define S 3

// ws layout (floats):
//   [0..15]   sums[9] (zeroed by prep, atomicAdd'd by k1)
//   [16..31]  bias2[9]
//   [32..]    W2K[9][256]  (k-major, k = s*3+t)
static constexpr int WS_SUMS  = 0;
static constexpr int WS_BIAS2 = 16;
static constexpr int WS_W2    = 32;

// ---------------------------------------------------------------------------
// prep: W2K[k][e'] = sum_em WQ[s,em] * exten_w[(em*3+t)*E + e'],  k = s*3+t
//       bias2[k]  = sum_em WQ[s,em] * exten_b[em*3+t]
//       zero the 9 softmax-denominator accumulators
// 9 blocks x 256 threads
// ---------------------------------------------------------------------------
__global__ __launch_bounds__(256) void prep(const float* __restrict__ exten_w,
                                            const float* __restrict__ exten_b,
                                            const float* __restrict__ WQ,
                                            float* __restrict__ ws) {
    int tid = blockIdx.x * 256 + threadIdx.x;   // 0..2303
    int k = tid >> 8;                           // 0..8
    int e = tid & 255;
    int s = k / 3, t = k - s * 3;
    float acc = 0.f;
    for (int em = 0; em < E; ++em)
        acc += WQ[s * E + em] * exten_w[(em * 3 + t) * E + e];
    ws[WS_W2 + k * E + e] = acc;

    if (tid < 16) ws[WS_SUMS + tid] = 0.f;
    if (tid >= 256 && tid < 256 + 9) {          // block 1, threads 0..8
        int kk = tid - 256;
        int ss = kk / 3, tt = kk - ss * 3;
        float b2 = 0.f;
        for (int em = 0; em < E; ++em)
            b2 += WQ[ss * E + em] * exten_b[em * 3 + tt];
        ws[WS_BIAS2 + kk] = b2;
    }
}

// ---------------------------------------------------------------------------
// k1: per-thread row.  Q[b] = W2 @ x[b] + bias2  (9 values)
//     - store Q into d_out[b*256 + 0..8]  (row-private slice, k2 reads it back)
//     - scores = Q Q^T / 16, es = exp(scores)
//     - wave butterfly reduce 9 sums -> block reduce -> 9 global atomicAdds
// 1024 blocks x 256 threads (one thread per row)
// ---------------------------------------------------------------------------
__global__ __launch_bounds__(256) void k1(const float* __restrict__ x,
                                          const float* __restrict__ wsc,
                                          float* __restrict__ out,
                                          float* __restrict__ wsa) {
    __shared__ __align__(16) float w2[9 * 256];
    __shared__ float bias2s[9];
    __shared__ float bsum[9 * 4];

    for (int i = threadIdx.x; i < 9 * 256; i += 256) w2[i] = wsc[WS_W2 + i];
    if (threadIdx.x < 9) bias2s[threadIdx.x] = wsc[WS_BIAS2 + threadIdx.x];
    __syncthreads();

    const int row = blockIdx.x * 256 + threadIdx.x;
    const float4* __restrict__ xr = (const float4*)(x + (size_t)row * E);

    float acc[9];
#pragma unroll
    for (int k = 0; k < 9; ++k) acc[k] = bias2s[k];

#pragma unroll 8
    for (int j = 0; j < 64; ++j) {
        const float4 xv = xr[j];
#pragma unroll
        for (int k = 0; k < 9; ++k) {
            const float4 w = *(const float4*)&w2[k * E + j * 4];
            acc[k] += xv.x * w.x;
            acc[k] += xv.y * w.y;
            acc[k] += xv.z * w.z;
            acc[k] += xv.w * w.w;
        }
    }

    // stash Q in this row's own output slice (overwritten by k2 after it reads)
    float* orow = out + (size_t)row * E;
    *(float4*)&orow[0] = make_float4(acc[0], acc[1], acc[2], acc[3]);
    *(float4*)&orow[4] = make_float4(acc[4], acc[5], acc[6], acc[7]);
    orow[8] = acc[8];

    // scores -> exp
    float es[9];
#pragma unroll
    for (int s = 0; s < 3; ++s)
#pragma unroll
        for (int u = 0; u < 3; ++u) {
            float sc = (acc[s * 3 + 0] * acc[u * 3 + 0] +
                        acc[s * 3 + 1] * acc[u * 3 + 1] +
                        acc[s * 3 + 2] * acc[u * 3 + 2]) * 0.0625f;
            es[s * 3 + u] = __expf(sc);
        }

    // butterfly reduce each of 9 values across the 64-lane wave
#pragma unroll
    for (int k = 0; k < 9; ++k) {
        float v = es[k];
#pragma unroll
        for (int m = 32; m >= 1; m >>= 1) v += __shfl_xor(v, m, 64);
        es[k] = v;
    }
    const int lane = threadIdx.x & 63;
    const int wv = threadIdx.x >> 6;
    if (lane == 0) {
#pragma unroll
        for (int k = 0; k < 9; ++k) bsum[wv * 9 + k] = es[k];
    }
    __syncthreads();
    if (threadIdx.x < 9) {
        float v = bsum[threadIdx.x] + bsum[9 + threadIdx.x] +
                  bsum[18 + threadIdx.x] + bsum[27 + threadIdx.x];
        atomicAdd(&wsa[WS_SUMS + threadIdx.x], v);
    }
}

// ---------------------------------------------------------------------------
// k2: per-thread row.  Reload Q (bit-exact), recompute scores/exp (identical
//     rounding to k1), att = exp/sum, ctx = att@Q, out = shrink_w@ctx+shrink_b
// 1024 blocks x 256 threads
// ---------------------------------------------------------------------------
__global__ __launch_bounds__(256) void k2(const float* __restrict__ shrink_w,
                                          const float* __restrict__ shrink_b,
                                          const float* __restrict__ wsc,
                                          float* __restrict__ out) {
    __shared__ __align__(16) float swk[9 * 256];   // [k][e]
    __shared__ __align__(16) float shb[256];
    __shared__ float inv_s[9];

    for (int i = threadIdx.x; i < 9 * 256; i += 256) {
        int e = i / 9, k = i - e * 9;
        swk[k * 256 + e] = shrink_w[i];
    }
    shb[threadIdx.x] = shrink_b[threadIdx.x];
    if (threadIdx.x < 9) inv_s[threadIdx.x] = 1.0f / wsc[WS_SUMS + threadIdx.x];
    __syncthreads();

    const int row = blockIdx.x * 256 + threadIdx.x;
    float* orow = out + (size_t)row * E;

    // reload Q (same bits k1 stored)
    float q[9];
    {
        float4 a = *(const float4*)&orow[0];
        float4 b = *(const float4*)&orow[4];
        q[0] = a.x; q[1] = a.y; q[2] = a.z; q[3] = a.w;
        q[4] = b.x; q[5] = b.y; q[6] = b.z; q[7] = b.w;
        q[8] = orow[8];
    }

    float att[9];
#pragma unroll
    for (int s = 0; s < 3; ++s)
#pragma unroll
        for (int u = 0; u < 3; ++u) {
            float sc = (q[s * 3 + 0] * q[u * 3 + 0] +
                        q[s * 3 + 1] * q[u * 3 + 1] +
                        q[s * 3 + 2] * q[u * 3 + 2]) * 0.0625f;
            att[s * 3 + u] = __expf(sc) * inv_s[s * 3 + u];
        }

    float ctx[9];
#pragma unroll
    for (int s = 0; s < 3; ++s)
#pragma unroll
        for (int t = 0; t < 3; ++t) {
            ctx[s * 3 + t] = att[s * 3 + 0] * q[0 * 3 + t] +
                             att[s * 3 + 1] * q[1 * 3 + t] +
                             att[s * 3 + 2] * q[2 * 3 + t];
        }

#pragma unroll 8
    for (int j = 0; j < 64; ++j) {
        const int e0 = j * 4;
        float4 o = *(const float4*)&shb[e0];
#pragma unroll
        for (int k = 0; k < 9; ++k) {
            const float4 w = *(const float4*)&swk[k * 256 + e0];
            o.x += ctx[k] * w.x;
            o.y += ctx[k] * w.y;
            o.z += ctx[k] * w.z;
            o.w += ctx[k] * w.w;
        }
        *(float4*)&orow[e0] = o;
    }
}

extern "C" void kernel_launch(void* const* d_in, const int* in_sizes, int n_in,
                              void* d_out, int out_size, void* d_ws, size_t ws_size,
                              hipStream_t stream) {
    const float* x        = (const float*)d_in[0];
    const float* exten_w  = (const float*)d_in[1];
    const float* exten_b  = (const float*)d_in[2];
    const float* WQ       = (const float*)d_in[3];
    const float* shrink_w = (const float*)d_in[4];
    const float* shrink_b = (const float*)d_in[5];
    float* out = (float*)d_out;
    float* ws  = (float*)d_ws;

    prep<<<9, 256, 0, stream>>>(exten_w, exten_b, WQ, ws);
    k1<<<1024, 256, 0, stream>>>(x, ws, out, ws);
    k2<<<1024, 256, 0, stream>>>(shrink_w, shrink_b, ws, out);
}

// Round 3
// 579.413 us; speedup vs baseline: 1.2877x; 1.2877x over previous
//
#include <hip/hip_runtime.h>

#define E 256
#define NROWS 262144

// ws layout (floats):
//   [0..15]    sums[9]   (zeroed by prep, atomicAdd'd by k1)
//   [16..31]   bias2[9]
//   [32..2335] W2K[9][256]  (k-major, k = s*3+t)
//   [4096..]   Q compact [NROWS][12]  (if ws_size permits)
static constexpr int WS_SUMS  = 0;
static constexpr int WS_BIAS2 = 16;
static constexpr int WS_W2    = 32;
static constexpr int WS_Q     = 4096;

__device__ __forceinline__ void gload16(const float* g, float* l) {
    __builtin_amdgcn_global_load_lds(
        (const __attribute__((address_space(1))) void*)g,
        (__attribute__((address_space(3))) void*)l, 16, 0, 0);
}

// identical expression in k1 and k2 -> bit-identical softmax numerators
__device__ __forceinline__ void scores_exp9(const float* q, float* es) {
#pragma unroll
    for (int s = 0; s < 3; ++s)
#pragma unroll
        for (int u = 0; u < 3; ++u) {
            float sc = (q[s*3+0]*q[u*3+0] + q[s*3+1]*q[u*3+1] +
                        q[s*3+2]*q[u*3+2]) * 0.0625f;
            es[s*3+u] = __expf(sc);
        }
}

// ---------------------------------------------------------------------------
// prep: W2K[k][e'] = sum_em WQ[s,em]*exten_w[(em*3+t)*E+e'];  bias2; zero sums
// 9 blocks x 256 threads; e'=tid&255 consecutive -> coalesced row reads
// ---------------------------------------------------------------------------
__global__ __launch_bounds__(256) void prep(const float* __restrict__ exten_w,
                                            const float* __restrict__ exten_b,
                                            const float* __restrict__ WQ,
                                            float* __restrict__ ws) {
    int tid = blockIdx.x * 256 + threadIdx.x;
    int k = tid >> 8;
    int e = tid & 255;
    int s = k / 3, t = k - s * 3;
    float acc = 0.f;
#pragma unroll 8
    for (int em = 0; em < E; ++em)
        acc += WQ[s * E + em] * exten_w[(em * 3 + t) * E + e];
    ws[WS_W2 + k * E + e] = acc;

    if (tid < 16) ws[WS_SUMS + tid] = 0.f;
    if (tid >= 256 && tid < 256 + 9) {
        int kk = tid - 256;
        int ss = kk / 3, tt = kk - ss * 3;
        float b2 = 0.f;
#pragma unroll 8
        for (int em = 0; em < E; ++em)
            b2 += WQ[ss * E + em] * exten_b[em * 3 + tt];
        ws[WS_BIAS2 + kk] = b2;
    }
}

// ---------------------------------------------------------------------------
// k1: 1024 blocks x 256 threads; 4 tiles of 64 rows per block.
//  stage x tile (gload_lds, coalesced) -> padded LDS [64][260]
//  wave w computes elements [64w,64w+64) of all 64 rows (lane=row)
//  partials reduced via LDS; Q -> compact global; exp-sums accumulated,
//  9 atomicAdds per block at the end.
// ---------------------------------------------------------------------------
__global__ __launch_bounds__(256) void k1(const float* __restrict__ x,
                                          const float* wsc,
                                          float* qout, long long qstride,
                                          float* sums) {
    __shared__ __align__(16) float lds[18960];
    float* xT   = lds;            // [64][260] floats (rows padded to 65 units)
    float* part = lds;            // overlay: [4][64][9] = 2304 floats
    float* qred = lds + 2304;     // overlay: [64][12]  = 768 floats
    float* w2   = lds + 16640;    // [9][256]
    float* b2   = lds + 18944;    // [9]

    for (int i = threadIdx.x; i < 576; i += 256)
        ((float4*)w2)[i] = ((const float4*)(wsc + WS_W2))[i];
    if (threadIdx.x < 9) b2[threadIdx.x] = wsc[WS_BIAS2 + threadIdx.x];

    const int wv   = threadIdx.x >> 6;
    const int lane = threadIdx.x & 63;
    float sum_es[9];
#pragma unroll
    for (int k = 0; k < 9; ++k) sum_es[k] = 0.f;

    __syncthreads();

    for (int tile = 0; tile < 4; ++tile) {
        const size_t base = (size_t)blockIdx.x * 256 + (size_t)tile * 64;

        // ---- stage: each wave loads 16 rows, 1024B per instruction ----
#pragma unroll
        for (int i = 0; i < 16; ++i) {
            const int r = wv * 16 + i;
            gload16(x + (base + r) * E + lane * 4, &xT[r * 260]);
        }
        __syncthreads();            // drains vmcnt before LDS reads

        // ---- compute: lane = row, wave = 64-element chunk ----
        float acc[9];
#pragma unroll
        for (int k = 0; k < 9; ++k) acc[k] = 0.f;
        {
            const float* xr = &xT[lane * 260 + wv * 64];
            const float* wr = &w2[wv * 64];
#pragma unroll
            for (int j = 0; j < 16; ++j) {
                const float4 xv = *(const float4*)&xr[j * 4];
#pragma unroll
                for (int k = 0; k < 9; ++k) {
                    const float4 w4 = *(const float4*)&wr[k * 256 + j * 4];
                    acc[k] += xv.x * w4.x + xv.y * w4.y +
                              xv.z * w4.z + xv.w * w4.w;
                }
            }
        }
        __syncthreads();            // x reads done -> overlay region writable

        {
            float* pp = &part[(wv * 64 + lane) * 9];
#pragma unroll
            for (int k = 0; k < 9; ++k) pp[k] = acc[k];
        }
        __syncthreads();

        // ---- reduce 4 wave-partials + bias -> qred[64][12] (pad k=9..11=0)
        for (int o = threadIdx.x; o < 768; o += 256) {
            const int row = o / 12, k = o - row * 12;
            float v = 0.f;
            if (k < 9) {
                const int p = row * 9 + k;
                v = part[p] + part[576 + p] + part[1152 + p] + part[1728 + p]
                    + b2[k];
            }
            qred[row * 12 + k] = v;
        }
        __syncthreads();

        // ---- Q -> global (coalesced-ish, 192 threads) ----
        if (threadIdx.x < 192) {
            const int row = threadIdx.x / 3, wq = threadIdx.x - row * 3;
            *(float4*)&qout[(base + row) * (size_t)qstride + wq * 4] =
                *(const float4*)&qred[row * 12 + wq * 4];
        }
        // ---- exp partial sums (threads < 64 = wave 0) ----
        if (threadIdx.x < 64) {
            float es[9];
            scores_exp9(&qred[threadIdx.x * 12], es);
#pragma unroll
            for (int k = 0; k < 9; ++k) sum_es[k] += es[k];
        }
        __syncthreads();            // before next tile's stage overwrites
    }

    if (threadIdx.x < 64) {
#pragma unroll
        for (int k = 0; k < 9; ++k) {
            float v = sum_es[k];
#pragma unroll
            for (int m = 32; m >= 1; m >>= 1) v += __shfl_xor(v, m, 64);
            if (lane == 0) atomicAdd(&sums[k], v);
        }
    }
}

// ---------------------------------------------------------------------------
// k2: 1024 blocks x 256 threads; 4 tiles of 64 rows.
//  stage Q tile -> LDS; per-thread (lane=row, wave=chunk) compute att/ctx and
//  the 64-element output chunk into padded LDS; then fully-coalesced writeout.
// ---------------------------------------------------------------------------
__global__ __launch_bounds__(256) void k2(const float* __restrict__ shrink_w,
                                          const float* __restrict__ shrink_b,
                                          const float* wsc,
                                          const float* qin, long long qstride,
                                          float* out) {
    __shared__ __align__(16) float o_t[64 * 260];
    __shared__ __align__(16) float swk[9 * 256];   // [k][e]
    __shared__ __align__(16) float shb[256];
    __shared__ __align__(16) float qs[64 * 12];
    __shared__ float inv_s[16];

    for (int i = threadIdx.x; i < 2304; i += 256) {
        const int e = i / 9, k = i - e * 9;
        swk[k * 256 + e] = shrink_w[i];
    }
    shb[threadIdx.x] = shrink_b[threadIdx.x];
    if (threadIdx.x < 9) inv_s[threadIdx.x] = 1.0f / wsc[WS_SUMS + threadIdx.x];

    const int wv   = threadIdx.x >> 6;
    const int lane = threadIdx.x & 63;
    __syncthreads();

    for (int tile = 0; tile < 4; ++tile) {
        const size_t base = (size_t)blockIdx.x * 256 + (size_t)tile * 64;

        if (threadIdx.x < 192) {
            const int row = threadIdx.x / 3, wq = threadIdx.x - row * 3;
            *(float4*)&qs[row * 12 + wq * 4] =
                *(const float4*)&qin[(base + row) * (size_t)qstride + wq * 4];
        }
        __syncthreads();

        // per-thread: row=lane, chunk=wv (redundant ctx across 4 waves, cheap)
        float es[9], ctx[9];
        const float* q = &qs[lane * 12];
        scores_exp9(q, es);
#pragma unroll
        for (int s = 0; s < 3; ++s) {
            const float a0 = es[s*3+0] * inv_s[s*3+0];
            const float a1 = es[s*3+1] * inv_s[s*3+1];
            const float a2 = es[s*3+2] * inv_s[s*3+2];
#pragma unroll
            for (int t = 0; t < 3; ++t)
                ctx[s*3+t] = a0 * q[0*3+t] + a1 * q[1*3+t] + a2 * q[2*3+t];
        }

        {
            float* orow     = &o_t[lane * 260 + wv * 64];
            const float* wr = &swk[wv * 64];
            const float* bb = &shb[wv * 64];
#pragma unroll
            for (int j = 0; j < 16; ++j) {
                float4 o = *(const float4*)&bb[j * 4];
#pragma unroll
                for (int k = 0; k < 9; ++k) {
                    const float4 w = *(const float4*)&wr[k * 256 + j * 4];
                    o.x += ctx[k] * w.x;  o.y += ctx[k] * w.y;
                    o.z += ctx[k] * w.z;  o.w += ctx[k] * w.w;
                }
                *(float4*)&orow[j * 4] = o;
            }
        }
        __syncthreads();

        // ---- coalesced writeout: 64 rows x 64 float4 = 4096 float4 units,
        //      256 threads -> 16 iterations (round-2 bug: was 4) ----
        {
            float* og = out + base * E;
#pragma unroll
            for (int it = 0; it < 16; ++it) {
                const int G = it * 256 + threadIdx.x;   // float4-unit index
                const int row = G >> 6, v = G & 63;
                *(float4*)&og[G * 4] = *(const float4*)&o_t[row * 260 + v * 4];
            }
        }
        __syncthreads();
    }
}

extern "C" void kernel_launch(void* const* d_in, const int* in_sizes, int n_in,
                              void* d_out, int out_size, void* d_ws, size_t ws_size,
                              hipStream_t stream) {
    const float* x        = (const float*)d_in[0];
    const float* exten_w  = (const float*)d_in[1];
    const float* exten_b  = (const float*)d_in[2];
    const float* WQ       = (const float*)d_in[3];
    const float* shrink_w = (const float*)d_in[4];
    const float* shrink_b = (const float*)d_in[5];
    float* out = (float*)d_out;
    float* ws  = (float*)d_ws;

    // compact Q buffer in ws if it fits, else stash Q in out rows (stride 256)
    const size_t qneed = ((size_t)NROWS * 12 + WS_Q) * sizeof(float);
    const bool usews = ws_size >= qneed;
    float* qbuf = usews ? (ws + WS_Q) : out;
    const long long qstride = usews ? 12 : 256;

    prep<<<9, 256, 0, stream>>>(exten_w, exten_b, WQ, ws);
    k1<<<1024, 256, 0, stream>>>(x, ws, qbuf, qstride, ws + WS_SUMS);
    k2<<<1024, 256, 0, stream>>>(shrink_w, shrink_b, ws, qbuf, qstride, out);
}